// Round 12
// baseline (413.738 us; speedup 1.0000x reference)
//
#include <hip/hip_runtime.h>

// GenericVNet: out = L(x) @ gradE(x) + V(x) (V(x)^T gradS(x))
// D=4, H=32, R=4, B=1M, fp32. VALU compute-bound (~10.5 GFLOP, 32 MB HBM).
//
// History:
//   R2  attrs-none:        AGPR shuttle, occ 33%, 329us
//   R3  lb(256,5):         scratch spill 35MB, 297us
//   R7  lb(256,3)+pk:      spill 17MB, occ 42%, 262us
//   R10 waves_per_eu(4,4): spill 40MB, 361us  <- allocator pins VGPR=64
//   R11 chunked-recompute: VGPR=44, WRITE=16.4MB (NO SPILL), occ 49%,
//       VALUBusy 85%, 157.7us. Structural liveness fix > attributes.
// R12: R11 still issues ~10.5k VALU slots/sample vs ~3.5-5.4k ideal.
//   Test: fully unroll net + kc loops (all weight addresses become
//   compile-time constants -> pure s_load batches, no SALU addr math, no
//   branch overhead, cross-chunk scheduling freedom). Liveness structure
//   (h1 never fully materialized) unchanged. Clean A/B vs R11.

namespace {

constexpr int D = 4;
constexpr int H = 32;
constexpr int H2 = H / 2;
constexpr int R = 4;

typedef float v2f __attribute__((ext_vector_type(2)));

__device__ __forceinline__ v2f fma2(v2f a, v2f b, v2f c) {
  return __builtin_elementwise_fma(a, b, c);
}

__device__ __forceinline__ float fast_rcp(float v) {
#if defined(__has_builtin)
#if __has_builtin(__builtin_amdgcn_rcpf)
  return __builtin_amdgcn_rcpf(v);
#else
  return 1.0f / v;
#endif
#else
  return 1.0f / v;
#endif
}

__device__ __forceinline__ float fast_exp2(float v) {
#if defined(__has_builtin)
#if __has_builtin(__builtin_amdgcn_exp2f)
  return __builtin_amdgcn_exp2f(v);
#else
  return exp2f(v);
#endif
#else
  return exp2f(v);
#endif
}

__device__ __forceinline__ float fast_tanh(float v) {
  // tanh(v) = 1 - 2/(exp(2v)+1); exp(2v) = exp2(v * 2*log2(e)).
  float e = fast_exp2(v * 2.885390081777926f);
  return 1.0f - 2.0f * fast_rcp(e + 1.0f);
}

__device__ __forceinline__ v2f tanh2(v2f v) {
  v2f r;
  r.x = fast_tanh(v.x);
  r.y = fast_tanh(v.y);
  return r;
}

// Forward+backward of one scalar net; force-inlined twice with distinct
// constant kernarg pointers so every weight address is a literal offset.
__device__ __forceinline__ void net_grad(
    const float xr[D],
    const float* __restrict__ w1, const float* __restrict__ b1,
    const float* __restrict__ w2, const float* __restrict__ b2,
    const float* __restrict__ w3, float grad[D]) {
  const v2f* __restrict__ w1p = reinterpret_cast<const v2f*>(w1);
  const v2f* __restrict__ b1p = reinterpret_cast<const v2f*>(b1);
  const v2f* __restrict__ w2p = reinterpret_cast<const v2f*>(w2);
  const v2f* __restrict__ b2p = reinterpret_cast<const v2f*>(b2);
  const v2f* __restrict__ w3p = reinterpret_cast<const v2f*>(w3);
  const v2f one2 = {1.0f, 1.0f};

  // ---- Phase A: g2 = (x@W1 -> tanh) @ W2 accumulation; h1 recomputed in
  //      chunks of 8 so it is never fully live ----
  v2f g2[H2];
#pragma unroll
  for (int j2 = 0; j2 < H2; ++j2) g2[j2] = b2p[j2];

#pragma unroll
  for (int kc = 0; kc < 4; ++kc) {
    v2f hp[4];
#pragma unroll
    for (int t2 = 0; t2 < 4; ++t2) hp[t2] = b1p[kc * 4 + t2];
#pragma unroll
    for (int i = 0; i < D; ++i) {
      v2f xi = {xr[i], xr[i]};
#pragma unroll
      for (int t2 = 0; t2 < 4; ++t2)
        hp[t2] = fma2(xi, w1p[i * H2 + kc * 4 + t2], hp[t2]);
    }
#pragma unroll
    for (int t2 = 0; t2 < 4; ++t2) hp[t2] = tanh2(hp[t2]);

#pragma unroll
    for (int t = 0; t < 8; ++t) {
      float hk = (t & 1) ? hp[t >> 1].y : hp[t >> 1].x;
      v2f hb = {hk, hk};
      int k = kc * 8 + t;
#pragma unroll
      for (int j2 = 0; j2 < H2; ++j2)
        g2[j2] = fma2(hb, w2p[k * H2 + j2], g2[j2]);
    }
  }

  // g2: pre2 -> d_pre2 = w3 * (1 - tanh(pre2)^2), in place
#pragma unroll
  for (int j2 = 0; j2 < H2; ++j2) {
    v2f t = tanh2(g2[j2]);
    g2[j2] = w3p[j2] * (one2 - t * t);
  }

  // ---- Phase B: grad[i] = sum_k w1[i,k]*(1-h1k^2)*(w2[k,:]. g2),
  //      h1 recomputed per chunk again ----
  float acc[D] = {0.0f, 0.0f, 0.0f, 0.0f};
#pragma unroll
  for (int kc = 0; kc < 4; ++kc) {
    v2f hp[4];
#pragma unroll
    for (int t2 = 0; t2 < 4; ++t2) hp[t2] = b1p[kc * 4 + t2];
#pragma unroll
    for (int i = 0; i < D; ++i) {
      v2f xi = {xr[i], xr[i]};
#pragma unroll
      for (int t2 = 0; t2 < 4; ++t2)
        hp[t2] = fma2(xi, w1p[i * H2 + kc * 4 + t2], hp[t2]);
    }
#pragma unroll
    for (int t2 = 0; t2 < 4; ++t2) hp[t2] = tanh2(hp[t2]);

#pragma unroll
    for (int t = 0; t < 8; ++t) {
      int k = kc * 8 + t;
      float hk = (t & 1) ? hp[t >> 1].y : hp[t >> 1].x;
      v2f s2 = {0.0f, 0.0f};
#pragma unroll
      for (int j2 = 0; j2 < H2; ++j2)
        s2 = fma2(w2p[k * H2 + j2], g2[j2], s2);
      float s = (s2.x + s2.y) * (1.0f - hk * hk);
#pragma unroll
      for (int i = 0; i < D; ++i) acc[i] = fmaf(w1[i * H + k], s, acc[i]);
    }
  }

#pragma unroll
  for (int i = 0; i < D; ++i) grad[i] = acc[i];
}

__global__ __launch_bounds__(256) void vnet_kernel(
    const float* __restrict__ x,
    const float* __restrict__ Ew1, const float* __restrict__ Eb1,
    const float* __restrict__ Ew2, const float* __restrict__ Eb2,
    const float* __restrict__ Ew3, const float* __restrict__ Eb3,
    const float* __restrict__ Sw1, const float* __restrict__ Sb1,
    const float* __restrict__ Sw2, const float* __restrict__ Sb2,
    const float* __restrict__ Sw3, const float* __restrict__ Sb3,
    const float* __restrict__ Lw, const float* __restrict__ Lb,
    const float* __restrict__ Mw, const float* __restrict__ Mb,
    float* __restrict__ out, int n) {
  int tid = blockIdx.x * blockDim.x + threadIdx.x;
  if (tid >= n) return;

  float4 xv = reinterpret_cast<const float4*>(x)[tid];
  float xr[D] = {xv.x, xv.y, xv.z, xv.w};

  // Two fully-inlined net evaluations with literal weight addressing.
  float gE[D], gS[D];
  net_grad(xr, Ew1, Eb1, Ew2, Eb2, Ew3, gE);
  net_grad(xr, Sw1, Sb1, Sw2, Sb2, Sw3, gS);

  // ---- L head: Bm = x @ Lw + Lb (16 outputs), packed over e ----
  v2f Bmp[D * D / 2];
  {
    const v2f* __restrict__ Lbp = reinterpret_cast<const v2f*>(Lb);
    const v2f* __restrict__ Lwp = reinterpret_cast<const v2f*>(Lw);
#pragma unroll
    for (int e2 = 0; e2 < D * D / 2; ++e2) Bmp[e2] = Lbp[e2];
#pragma unroll
    for (int i = 0; i < D; ++i) {
      v2f xi = {xr[i], xr[i]};
#pragma unroll
      for (int e2 = 0; e2 < D * D / 2; ++e2)
        Bmp[e2] = fma2(xi, Lwp[i * (D * D / 2) + e2], Bmp[e2]);
    }
  }
  const float* Bm = reinterpret_cast<const float*>(Bmp);

  // ---- M head: V = x @ Mw + Mb (16 outputs), packed over e ----
  v2f Vp[D * R / 2];
  {
    const v2f* __restrict__ Mbp = reinterpret_cast<const v2f*>(Mb);
    const v2f* __restrict__ Mwp = reinterpret_cast<const v2f*>(Mw);
#pragma unroll
    for (int e2 = 0; e2 < D * R / 2; ++e2) Vp[e2] = Mbp[e2];
#pragma unroll
    for (int i = 0; i < D; ++i) {
      v2f xi = {xr[i], xr[i]};
#pragma unroll
      for (int e2 = 0; e2 < D * R / 2; ++e2)
        Vp[e2] = fma2(xi, Mwp[i * (D * R / 2) + e2], Vp[e2]);
    }
  }
  const float* V = reinterpret_cast<const float*>(Vp);

  // u[r] = sum_i V[i][r] * gS[i]
  float u[R];
#pragma unroll
  for (int r = 0; r < R; ++r) {
    float a = 0.0f;
#pragma unroll
    for (int i = 0; i < D; ++i) a = fmaf(V[i * R + r], gS[i], a);
    u[r] = a;
  }

  // out[i] = sum_j (Bm[i][j]-Bm[j][i]) * gE[j] + sum_r V[i][r] * u[r]
  float o[D];
#pragma unroll
  for (int i = 0; i < D; ++i) {
    float a = 0.0f;
#pragma unroll
    for (int j = 0; j < D; ++j)
      a = fmaf(Bm[i * D + j] - Bm[j * D + i], gE[j], a);
#pragma unroll
    for (int r = 0; r < R; ++r) a = fmaf(V[i * R + r], u[r], a);
    o[i] = a;
  }

  reinterpret_cast<float4*>(out)[tid] = make_float4(o[0], o[1], o[2], o[3]);
}

}  // namespace

extern "C" void kernel_launch(void* const* d_in, const int* in_sizes, int n_in,
                              void* d_out, int out_size, void* d_ws, size_t ws_size,
                              hipStream_t stream) {
  const float* x   = (const float*)d_in[0];
  const float* Ew1 = (const float*)d_in[1];
  const float* Eb1 = (const float*)d_in[2];
  const float* Ew2 = (const float*)d_in[3];
  const float* Eb2 = (const float*)d_in[4];
  const float* Ew3 = (const float*)d_in[5];
  const float* Eb3 = (const float*)d_in[6];
  const float* Sw1 = (const float*)d_in[7];
  const float* Sb1 = (const float*)d_in[8];
  const float* Sw2 = (const float*)d_in[9];
  const float* Sb2 = (const float*)d_in[10];
  const float* Sw3 = (const float*)d_in[11];
  const float* Sb3 = (const float*)d_in[12];
  const float* Lw  = (const float*)d_in[13];
  const float* Lb  = (const float*)d_in[14];
  const float* Mw  = (const float*)d_in[15];
  const float* Mb  = (const float*)d_in[16];
  float* out = (float*)d_out;

  int n = in_sizes[0] / D;  // number of samples
  const int block = 256;
  int grid = (n + block - 1) / block;
  vnet_kernel<<<grid, block, 0, stream>>>(x, Ew1, Eb1, Ew2, Eb2, Ew3, Eb3,
                                          Sw1, Sb1, Sw2, Sb2, Sw3, Sb3,
                                          Lw, Lb, Mw, Mb, out, n);
}

// Round 14
// 233.644 us; speedup vs baseline: 1.7708x; 1.7708x over previous
//
#include <hip/hip_runtime.h>

// GenericVNet: out = L(x) @ gradE(x) + V(x) (V(x)^T gradS(x))
// D=4, H=32, R=4, B=1M, fp32. VALU issue-bound.
//
// History:
//   R2  attrs-none:        AGPR shuttle, occ 33%, 329us
//   R3  lb(256,5):         scratch spill 35MB, 297us
//   R7  lb(256,3)+pk?:     spill 17MB, occ 42%, 262us
//   R10 waves_per_eu(4,4): spill 40MB, 361us  (allocator pins VGPR=64)
//   R11 chunked-recompute: VGPR=44, WRITE=16.4MB clean, occ 49%,
//       VALUBusy 85%, 157.7us  <- best; rolled loops are load-bearing
//   R12 full unroll:       VGPR=92, occ 22%, I-cache blown, 345us. REVERTED.
// R13/R14: R11 structure EXACTLY + inline-asm v_pk_fma_f32 in the 4 hot
//   loops (L1 fwd, g2-accum, hp-recompute, s2-dot). Theory: builtin v2f fma
//   was scalarized (measured 10.5k slots/sample ~= scalar estimate, not pk
//   estimate 5.1k). VALUBusy 85% => only slot REDUCTION helps.
//   (R13 never ran: acquisition timeout. Resubmitting unchanged.)

namespace {

constexpr int D = 4;
constexpr int H = 32;
constexpr int H2 = H / 2;
constexpr int R = 4;

typedef float v2f __attribute__((ext_vector_type(2)));

// Forced packed-fp32 FMA: d = w*b + c, w wave-uniform (SGPR pair).
__device__ __forceinline__ v2f pk_fma_sv(v2f w, v2f b, v2f c) {
  v2f d;
  asm("v_pk_fma_f32 %0, %1, %2, %3" : "=v"(d) : "s"(w), "v"(b), "v"(c));
  return d;
}

__device__ __forceinline__ v2f fma2(v2f a, v2f b, v2f c) {
  return __builtin_elementwise_fma(a, b, c);
}

__device__ __forceinline__ float fast_rcp(float v) {
#if defined(__has_builtin)
#if __has_builtin(__builtin_amdgcn_rcpf)
  return __builtin_amdgcn_rcpf(v);
#else
  return 1.0f / v;
#endif
#else
  return 1.0f / v;
#endif
}

__device__ __forceinline__ float fast_exp2(float v) {
#if defined(__has_builtin)
#if __has_builtin(__builtin_amdgcn_exp2f)
  return __builtin_amdgcn_exp2f(v);
#else
  return exp2f(v);
#endif
#else
  return exp2f(v);
#endif
}

__device__ __forceinline__ float fast_tanh(float v) {
  // tanh(v) = 1 - 2/(exp(2v)+1); exp(2v) = exp2(v * 2*log2(e)).
  float e = fast_exp2(v * 2.885390081777926f);
  return 1.0f - 2.0f * fast_rcp(e + 1.0f);
}

__device__ __forceinline__ v2f tanh2(v2f v) {
  v2f r;
  r.x = fast_tanh(v.x);
  r.y = fast_tanh(v.y);
  return r;
}

__global__ __launch_bounds__(256) void vnet_kernel(
    const float* __restrict__ x,
    const float* __restrict__ Ew1, const float* __restrict__ Eb1,
    const float* __restrict__ Ew2, const float* __restrict__ Eb2,
    const float* __restrict__ Ew3, const float* __restrict__ Eb3,
    const float* __restrict__ Sw1, const float* __restrict__ Sb1,
    const float* __restrict__ Sw2, const float* __restrict__ Sb2,
    const float* __restrict__ Sw3, const float* __restrict__ Sb3,
    const float* __restrict__ Lw, const float* __restrict__ Lb,
    const float* __restrict__ Mw, const float* __restrict__ Mb,
    float* __restrict__ out, int n) {
  int tid = blockIdx.x * blockDim.x + threadIdx.x;
  if (tid >= n) return;

  float4 xv = reinterpret_cast<const float4*>(x)[tid];
  float xr[D] = {xv.x, xv.y, xv.z, xv.w};

  float gE[D], gS[D];
  const v2f one2 = {1.0f, 1.0f};

  // One code copy for both MLPs; weight pointers are wave-uniform selects so
  // all weight reads stay scalar (s_load) feeding v_pk_fma_f32 as SGPR64.
#pragma unroll 1
  for (int net = 0; net < 2; ++net) {
    const float* __restrict__ w1 = net ? Sw1 : Ew1;
    const v2f* __restrict__ w1p = reinterpret_cast<const v2f*>(w1);
    const v2f* __restrict__ b1p =
        reinterpret_cast<const v2f*>(net ? Sb1 : Eb1);
    const v2f* __restrict__ w2p =
        reinterpret_cast<const v2f*>(net ? Sw2 : Ew2);
    const v2f* __restrict__ b2p =
        reinterpret_cast<const v2f*>(net ? Sb2 : Eb2);
    const v2f* __restrict__ w3p =
        reinterpret_cast<const v2f*>(net ? Sw3 : Ew3);

    // ---- Phase A: g2 = (x@W1 -> tanh) @ W2 accumulation; h1 recomputed in
    //      chunks of 8 so it is never fully live ----
    v2f g2[H2];
#pragma unroll
    for (int j2 = 0; j2 < H2; ++j2) g2[j2] = b2p[j2];

#pragma unroll 1
    for (int kc = 0; kc < 4; ++kc) {
      // recompute h1[kc*8 .. kc*8+7]
      v2f hp[4];
#pragma unroll
      for (int t2 = 0; t2 < 4; ++t2) hp[t2] = b1p[kc * 4 + t2];
#pragma unroll
      for (int i = 0; i < D; ++i) {
        v2f xi = {xr[i], xr[i]};
#pragma unroll
        for (int t2 = 0; t2 < 4; ++t2)
          hp[t2] = pk_fma_sv(w1p[i * H2 + kc * 4 + t2], xi, hp[t2]);
      }
#pragma unroll
      for (int t2 = 0; t2 < 4; ++t2) hp[t2] = tanh2(hp[t2]);

      // g2 += h1[k] * w2[k,:] for the chunk
#pragma unroll
      for (int t = 0; t < 8; ++t) {
        float hk = (t & 1) ? hp[t >> 1].y : hp[t >> 1].x;
        v2f hb = {hk, hk};
        int k = kc * 8 + t;
#pragma unroll
        for (int j2 = 0; j2 < H2; ++j2)
          g2[j2] = pk_fma_sv(w2p[k * H2 + j2], hb, g2[j2]);
      }
    }

    // g2: pre2 -> d_pre2 = w3 * (1 - tanh(pre2)^2), in place
#pragma unroll
    for (int j2 = 0; j2 < H2; ++j2) {
      v2f t = tanh2(g2[j2]);
      g2[j2] = w3p[j2] * (one2 - t * t);
    }

    // ---- Phase B: grad[i] = sum_k w1[i,k]*(1-h1k^2)*(w2[k,:].g2),
    //      h1 recomputed per chunk again ----
    float acc[D] = {0.0f, 0.0f, 0.0f, 0.0f};
#pragma unroll 1
    for (int kc = 0; kc < 4; ++kc) {
      v2f hp[4];
#pragma unroll
      for (int t2 = 0; t2 < 4; ++t2) hp[t2] = b1p[kc * 4 + t2];
#pragma unroll
      for (int i = 0; i < D; ++i) {
        v2f xi = {xr[i], xr[i]};
#pragma unroll
        for (int t2 = 0; t2 < 4; ++t2)
          hp[t2] = pk_fma_sv(w1p[i * H2 + kc * 4 + t2], xi, hp[t2]);
      }
#pragma unroll
      for (int t2 = 0; t2 < 4; ++t2) hp[t2] = tanh2(hp[t2]);

#pragma unroll
      for (int t = 0; t < 8; ++t) {
        int k = kc * 8 + t;
        float hk = (t & 1) ? hp[t >> 1].y : hp[t >> 1].x;
        v2f s2 = {0.0f, 0.0f};
#pragma unroll
        for (int j2 = 0; j2 < H2; ++j2)
          s2 = pk_fma_sv(w2p[k * H2 + j2], g2[j2], s2);
        float s = (s2.x + s2.y) * (1.0f - hk * hk);
#pragma unroll
        for (int i = 0; i < D; ++i) acc[i] = fmaf(w1[i * H + k], s, acc[i]);
      }
    }

    if (net == 0) {
#pragma unroll
      for (int i = 0; i < D; ++i) gE[i] = acc[i];
    } else {
#pragma unroll
      for (int i = 0; i < D; ++i) gS[i] = acc[i];
    }
  }

  // ---- L head: Bm = x @ Lw + Lb (16 outputs), packed over e ----
  v2f Bmp[D * D / 2];
  {
    const v2f* __restrict__ Lbp = reinterpret_cast<const v2f*>(Lb);
    const v2f* __restrict__ Lwp = reinterpret_cast<const v2f*>(Lw);
#pragma unroll
    for (int e2 = 0; e2 < D * D / 2; ++e2) Bmp[e2] = Lbp[e2];
#pragma unroll
    for (int i = 0; i < D; ++i) {
      v2f xi = {xr[i], xr[i]};
#pragma unroll
      for (int e2 = 0; e2 < D * D / 2; ++e2)
        Bmp[e2] = fma2(xi, Lwp[i * (D * D / 2) + e2], Bmp[e2]);
    }
  }
  const float* Bm = reinterpret_cast<const float*>(Bmp);

  // ---- M head: V = x @ Mw + Mb (16 outputs), packed over e ----
  v2f Vp[D * R / 2];
  {
    const v2f* __restrict__ Mbp = reinterpret_cast<const v2f*>(Mb);
    const v2f* __restrict__ Mwp = reinterpret_cast<const v2f*>(Mw);
#pragma unroll
    for (int e2 = 0; e2 < D * R / 2; ++e2) Vp[e2] = Mbp[e2];
#pragma unroll
    for (int i = 0; i < D; ++i) {
      v2f xi = {xr[i], xr[i]};
#pragma unroll
      for (int e2 = 0; e2 < D * R / 2; ++e2)
        Vp[e2] = fma2(xi, Mwp[i * (D * R / 2) + e2], Vp[e2]);
    }
  }
  const float* V = reinterpret_cast<const float*>(Vp);

  // u[r] = sum_i V[i][r] * gS[i]
  float u[R];
#pragma unroll
  for (int r = 0; r < R; ++r) {
    float a = 0.0f;
#pragma unroll
    for (int i = 0; i < D; ++i) a = fmaf(V[i * R + r], gS[i], a);
    u[r] = a;
  }

  // out[i] = sum_j (Bm[i][j]-Bm[j][i]) * gE[j] + sum_r V[i][r] * u[r]
  float o[D];
#pragma unroll
  for (int i = 0; i < D; ++i) {
    float a = 0.0f;
#pragma unroll
    for (int j = 0; j < D; ++j)
      a = fmaf(Bm[i * D + j] - Bm[j * D + i], gE[j], a);
#pragma unroll
    for (int r = 0; r < R; ++r) a = fmaf(V[i * R + r], u[r], a);
    o[i] = a;
  }

  reinterpret_cast<float4*>(out)[tid] = make_float4(o[0], o[1], o[2], o[3]);
}

}  // namespace

extern "C" void kernel_launch(void* const* d_in, const int* in_sizes, int n_in,
                              void* d_out, int out_size, void* d_ws, size_t ws_size,
                              hipStream_t stream) {
  const float* x   = (const float*)d_in[0];
  const float* Ew1 = (const float*)d_in[1];
  const float* Eb1 = (const float*)d_in[2];
  const float* Ew2 = (const float*)d_in[3];
  const float* Eb2 = (const float*)d_in[4];
  const float* Ew3 = (const float*)d_in[5];
  const float* Eb3 = (const float*)d_in[6];
  const float* Sw1 = (const float*)d_in[7];
  const float* Sb1 = (const float*)d_in[8];
  const float* Sw2 = (const float*)d_in[9];
  const float* Sb2 = (const float*)d_in[10];
  const float* Sw3 = (const float*)d_in[11];
  const float* Sb3 = (const float*)d_in[12];
  const float* Lw  = (const float*)d_in[13];
  const float* Lb  = (const float*)d_in[14];
  const float* Mw  = (const float*)d_in[15];
  const float* Mb  = (const float*)d_in[16];
  float* out = (float*)d_out;

  int n = in_sizes[0] / D;  // number of samples
  const int block = 256;
  int grid = (n + block - 1) / block;
  vnet_kernel<<<grid, block, 0, stream>>>(x, Ew1, Eb1, Ew2, Eb2, Ew3, Eb3,
                                          Sw1, Sb1, Sw2, Sb2, Sw3, Sb3,
                                          Lw, Lb, Mw, Mb, out, n);
}